// Round 1
// baseline (5781.174 us; speedup 1.0000x reference)
//
#include <hip/hip_runtime.h>
#include <math.h>

#define D 1024
#define H 16
#define DK 64
#define SQ 1024
#define NB 8
#define NROW (NB*SQ)   // 8192

// ---------------------------------------------------------------------------
// GEMM: C[i][j] = sum_k A[i][k] * W[j][k]  (+ bias, + optional residual)
// A: [M][1024] row-major, W: [1024][1024] row-major (we need x @ W.T, so both
// are dotted along their rows -> coalesced k access for both).
// MODE 0: scatter output to [B,H,S,DK] head layout
// MODE 1: out[i*1024+j] = acc + bias[j] + resid[i*1024+j]  (plain layout)
// ---------------------------------------------------------------------------
template<int MODE>
__global__ __launch_bounds__(256)
void gemm_bt(const float* __restrict__ A, const float* __restrict__ W,
             const float* __restrict__ bias, const float* __restrict__ resid,
             float* __restrict__ out)
{
    __shared__ float As[32][68];   // k-major, stride 68 floats = 272B (16B aligned)
    __shared__ float Bs[32][68];
    const int t  = threadIdx.x;
    const int tx = t & 15, ty = t >> 4;
    const int i0 = blockIdx.y * 64, j0 = blockIdx.x * 64;
    float acc[4][4] = {};
    for (int k0 = 0; k0 < 1024; k0 += 32) {
#pragma unroll
        for (int l = 0; l < 8; ++l) {
            int idx = t + l*256;           // 0..2047
            int row = idx >> 5, kk = idx & 31;
            As[kk][row] = A[(size_t)(i0+row)*1024 + k0 + kk];
            Bs[kk][row] = W[(size_t)(j0+row)*1024 + k0 + kk];
        }
        __syncthreads();
#pragma unroll
        for (int kk = 0; kk < 32; ++kk) {
            float4 a4 = *(const float4*)&As[kk][ty*4];
            float4 b4 = *(const float4*)&Bs[kk][tx*4];
            float ar[4] = {a4.x,a4.y,a4.z,a4.w};
            float br[4] = {b4.x,b4.y,b4.z,b4.w};
#pragma unroll
            for (int r = 0; r < 4; ++r)
#pragma unroll
                for (int c = 0; c < 4; ++c)
                    acc[r][c] = fmaf(ar[r], br[c], acc[r][c]);
        }
        __syncthreads();
    }
#pragma unroll
    for (int r = 0; r < 4; ++r) {
        int i = i0 + ty*4 + r;
#pragma unroll
        for (int c = 0; c < 4; ++c) {
            int j = j0 + tx*4 + c;
            float v = acc[r][c] + bias[j];
            if (MODE == 0) {
                int b = i >> 10, s = i & 1023, hh = j >> 6, d = j & 63;
                out[(((size_t)b*H + hh)*SQ + s)*DK + d] = v;
            } else {
                out[(size_t)i*1024 + j] = v + resid[(size_t)i*1024 + j];
            }
        }
    }
}

// ---------------------------------------------------------------------------
// Attention: one block per (b, h, 8-query tile). Q,K,V in [B,H,S,DK] layout.
// Scores for the 8 rows held in LDS (8x1024 fp32 = 32KB), softmax in-place,
// attn probabilities written to d_out, then PV from LDS-staged V tiles.
// Static LDS ~52KB -> 2 blocks/CU.
// ---------------------------------------------------------------------------
__global__ __launch_bounds__(256)
void attn_k(const float* __restrict__ Q, const float* __restrict__ K,
            const float* __restrict__ V, float* __restrict__ attn_out,
            float* __restrict__ ctx)
{
    __shared__ float Qs[8][68];
    __shared__ float KVs[64][68];
    __shared__ float Ps[8][1024];
    __shared__ float invr[8];

    const int t  = threadIdx.x;
    const int qt = blockIdx.x;          // 0..127 (8 queries each)
    const int hh = blockIdx.y;
    const int b  = blockIdx.z;
    const int bh = b*H + hh;
    const size_t qkvbase = (size_t)bh * SQ * DK;

    // stage Q tile (8 x 64)
    {
        const float* Qp = Q + qkvbase + (size_t)qt*8*DK;
#pragma unroll
        for (int l = 0; l < 2; ++l) {
            int idx = t + l*256;        // 0..511
            Qs[idx>>6][idx&63] = Qp[idx];
        }
    }
    __syncthreads();

    const int kq = t & 63;              // k-column within tile / dv
    const int q0 = (t >> 6) * 2;        // 2 queries per thread

    // ---- scores ----
    for (int kt = 0; kt < 16; ++kt) {
        const float* Kp = K + qkvbase + (size_t)kt*64*DK;
#pragma unroll
        for (int l = 0; l < 16; ++l) {
            int idx = t + l*256;        // 0..4095
            KVs[idx>>6][idx&63] = Kp[idx];
        }
        __syncthreads();
        float s[2] = {0.f, 0.f};
#pragma unroll
        for (int d4 = 0; d4 < 16; ++d4) {
            float4 kv = *(const float4*)&KVs[kq][d4*4];
#pragma unroll
            for (int r = 0; r < 2; ++r) {
                float4 qv = *(const float4*)&Qs[q0+r][d4*4];
                s[r] = fmaf(qv.x, kv.x, s[r]);
                s[r] = fmaf(qv.y, kv.y, s[r]);
                s[r] = fmaf(qv.z, kv.z, s[r]);
                s[r] = fmaf(qv.w, kv.w, s[r]);
            }
        }
#pragma unroll
        for (int r = 0; r < 2; ++r)
            Ps[q0+r][kt*64 + kq] = s[r] * 0.125f;   // 1/sqrt(64)
        __syncthreads();
    }

    // ---- softmax over each of the 8 rows (32 threads per row) ----
    {
        const int r = t >> 5, sub = t & 31;
        float m = -1e30f;
#pragma unroll
        for (int j = 0; j < 32; ++j) m = fmaxf(m, Ps[r][sub + j*32]);
#pragma unroll
        for (int o = 16; o >= 1; o >>= 1) m = fmaxf(m, __shfl_xor(m, o, 32));
        float ssum = 0.f;
#pragma unroll
        for (int j = 0; j < 32; ++j) {
            int c = sub + j*32;
            float e = __expf(Ps[r][c] - m);
            Ps[r][c] = e;               // keep unnormalized; fold 1/sum later
            ssum += e;
        }
#pragma unroll
        for (int o = 16; o >= 1; o >>= 1) ssum += __shfl_xor(ssum, o, 32);
        if (sub == 0) invr[r] = 1.0f / ssum;
    }
    __syncthreads();

    // ---- write attn probabilities (coalesced) ----
    {
        float* ap = attn_out + ((size_t)bh*SQ + (size_t)qt*8) * SQ;
#pragma unroll
        for (int l = 0; l < 32; ++l) {
            int idx = t + l*256;        // 0..8191
            int r = idx >> 10, c = idx & 1023;
            ap[(size_t)r*SQ + c] = Ps[r][c] * invr[r];
        }
    }

    // ---- PV ----
    float acc[2] = {0.f, 0.f};
    for (int kt = 0; kt < 16; ++kt) {
        __syncthreads();                // protect KVs from previous readers
        const float* Vp = V + qkvbase + (size_t)kt*64*DK;
#pragma unroll
        for (int l = 0; l < 16; ++l) {
            int idx = t + l*256;
            KVs[idx>>6][idx&63] = Vp[idx];
        }
        __syncthreads();
#pragma unroll
        for (int k2 = 0; k2 < 64; ++k2) {
            float v = KVs[k2][kq];
            int kc = kt*64 + k2;
#pragma unroll
            for (int r = 0; r < 2; ++r)
                acc[r] = fmaf(Ps[q0+r][kc], v, acc[r]);
        }
    }
    // write ctx in [B,S,D] layout (transpose heads back)
#pragma unroll
    for (int r = 0; r < 2; ++r) {
        int q = q0 + r;
        ctx[((size_t)b*SQ + (size_t)qt*8 + q)*D + hh*DK + kq] = acc[r] * invr[q];
    }
}

// ---------------------------------------------------------------------------
// LayerNorm: one block per row
// ---------------------------------------------------------------------------
__global__ __launch_bounds__(256)
void ln_k(const float* __restrict__ hbuf, const float* __restrict__ gamma,
          const float* __restrict__ beta, float* __restrict__ y)
{
    const int row = blockIdx.x;
    const float* hr = hbuf + (size_t)row * D;
    float v[4];
    float s = 0.f, sq = 0.f;
#pragma unroll
    for (int l = 0; l < 4; ++l) {
        v[l] = hr[threadIdx.x + l*256];
        s += v[l];
        sq = fmaf(v[l], v[l], sq);
    }
#pragma unroll
    for (int o = 32; o >= 1; o >>= 1) {
        s  += __shfl_down(s, o, 64);
        sq += __shfl_down(sq, o, 64);
    }
    __shared__ float rs_[4], rq_[4], mu_s, rstd_s;
    int wid = threadIdx.x >> 6;
    if ((threadIdx.x & 63) == 0) { rs_[wid] = s; rq_[wid] = sq; }
    __syncthreads();
    if (threadIdx.x == 0) {
        float S  = rs_[0]+rs_[1]+rs_[2]+rs_[3];
        float Q2 = rq_[0]+rq_[1]+rq_[2]+rq_[3];
        float mu  = S * (1.0f/1024.0f);
        float var = Q2 * (1.0f/1024.0f) - mu*mu;
        mu_s = mu;
        rstd_s = rsqrtf(var + 1e-5f);
    }
    __syncthreads();
    float mu = mu_s, rstd = rstd_s;
#pragma unroll
    for (int l = 0; l < 4; ++l) {
        int c = threadIdx.x + l*256;
        y[(size_t)row*D + c] = (v[l]-mu)*rstd*gamma[c] + beta[c];
    }
}

// ---------------------------------------------------------------------------
extern "C" void kernel_launch(void* const* d_in, const int* in_sizes, int n_in,
                              void* d_out, int out_size, void* d_ws, size_t ws_size,
                              hipStream_t stream)
{
    const float* x     = (const float*)d_in[0];
    const float* Wq    = (const float*)d_in[1];
    const float* bq    = (const float*)d_in[2];
    const float* Wk    = (const float*)d_in[3];
    const float* bk    = (const float*)d_in[4];
    const float* Wv    = (const float*)d_in[5];
    const float* bv    = (const float*)d_in[6];
    const float* Wo    = (const float*)d_in[7];
    const float* bo    = (const float*)d_in[8];
    const float* gamma = (const float*)d_in[9];
    const float* beta  = (const float*)d_in[10];

    float* y    = (float*)d_out;                     // [8,1024,1024]
    float* attn = (float*)d_out + (size_t)NROW * D;  // [8,16,1024,1024]

    const size_t SZ = (size_t)NROW * D;              // 8388608 floats = 32MB
    float* ws = (float*)d_ws;
    float* Qb = ws;            // [B,H,S,DK]
    float* Kb = ws + SZ;
    float* Vb = ws + 2*SZ;
    float* Cb = ws + 3*SZ;     // ctx [B,S,D]
    float* Hb = Qb;            // h reuses Q region (Q dead after attention)

    dim3 gg(16, 128), bb(256);
    gemm_bt<0><<<gg, bb, 0, stream>>>(x, Wq, bq, nullptr, Qb);
    gemm_bt<0><<<gg, bb, 0, stream>>>(x, Wk, bk, nullptr, Kb);
    gemm_bt<0><<<gg, bb, 0, stream>>>(x, Wv, bv, nullptr, Vb);

    dim3 ga(128, H, NB);
    attn_k<<<ga, 256, 0, stream>>>(Qb, Kb, Vb, attn, Cb);

    gemm_bt<1><<<gg, bb, 0, stream>>>(Cb, Wo, bo, x, Hb);

    ln_k<<<NROW, 256, 0, stream>>>(Hb, gamma, beta, y);
}

// Round 2
// 1362.839 us; speedup vs baseline: 4.2420x; 4.2420x over previous
//
#include <hip/hip_runtime.h>
#include <math.h>

#define D 1024
#define H 16
#define DK 64
#define SQ 1024
#define NB 8
#define NROW (NB*SQ)   // 8192

typedef __attribute__((ext_vector_type(8))) short bf16x8;
typedef __attribute__((ext_vector_type(4))) float f32x4;

__device__ __forceinline__ ushort f2bf(float x){
    unsigned u = __builtin_bit_cast(unsigned, x);
    u += 0x7FFFu + ((u >> 16) & 1u);
    return (ushort)(u >> 16);
}

__device__ __forceinline__ f32x4 mfma16(bf16x8 a, bf16x8 b, f32x4 c){
    return __builtin_amdgcn_mfma_f32_16x16x32_bf16(a, b, c, 0, 0, 0);
}

// ---------------------------------------------------------------------------
// GEMM: C[i][j] = sum_k A[i][k] * W[j][k]  (+ bias, + optional residual)
// MODE 0: scatter output to [B,H,S,DK] head layout
// MODE 1: out[i*1024+j] = acc + bias[j] + resid[i*1024+j]  (plain layout)
// MODE 2: scatter output to [B,H,DK,SQ] transposed head layout (for V)
// ---------------------------------------------------------------------------
template<int MODE>
__global__ __launch_bounds__(256)
void gemm_bt(const float* __restrict__ A, const float* __restrict__ W,
             const float* __restrict__ bias, const float* __restrict__ resid,
             float* __restrict__ out)
{
    __shared__ float As[32][68];
    __shared__ float Bs[32][68];
    const int t  = threadIdx.x;
    const int tx = t & 15, ty = t >> 4;
    const int i0 = blockIdx.y * 64, j0 = blockIdx.x * 64;
    float acc[4][4] = {};
    for (int k0 = 0; k0 < 1024; k0 += 32) {
#pragma unroll
        for (int l = 0; l < 8; ++l) {
            int idx = t + l*256;
            int row = idx >> 5, kk = idx & 31;
            As[kk][row] = A[(size_t)(i0+row)*1024 + k0 + kk];
            Bs[kk][row] = W[(size_t)(j0+row)*1024 + k0 + kk];
        }
        __syncthreads();
#pragma unroll
        for (int kk = 0; kk < 32; ++kk) {
            float4 a4 = *(const float4*)&As[kk][ty*4];
            float4 b4 = *(const float4*)&Bs[kk][tx*4];
            float ar[4] = {a4.x,a4.y,a4.z,a4.w};
            float br[4] = {b4.x,b4.y,b4.z,b4.w};
#pragma unroll
            for (int r = 0; r < 4; ++r)
#pragma unroll
                for (int c = 0; c < 4; ++c)
                    acc[r][c] = fmaf(ar[r], br[c], acc[r][c]);
        }
        __syncthreads();
    }
#pragma unroll
    for (int r = 0; r < 4; ++r) {
        int i = i0 + ty*4 + r;
#pragma unroll
        for (int c = 0; c < 4; ++c) {
            int j = j0 + tx*4 + c;
            float v = acc[r][c] + bias[j];
            if (MODE == 0) {
                int b = i >> 10, s = i & 1023, hh = j >> 6, d = j & 63;
                out[(((size_t)b*H + hh)*SQ + s)*DK + d] = v;
            } else if (MODE == 2) {
                int b = i >> 10, s = i & 1023, hh = j >> 6, d = j & 63;
                out[(((size_t)b*H + hh)*DK + d)*SQ + s] = v;
            } else {
                out[(size_t)i*1024 + j] = v + resid[(size_t)i*1024 + j];
            }
        }
    }
}

// ---------------------------------------------------------------------------
// Stage a 64x64 fp32 tile -> bf16 LDS with 16B-chunk XOR swizzle (chunk^=row&7)
// ---------------------------------------------------------------------------
__device__ __forceinline__ void stage64(const float* __restrict__ src, int rowstride,
                                        ushort* lds, int t)
{
    const int row = t >> 2, cseg = t & 3;
    const float* p = src + (size_t)row * rowstride + cseg * 16;
    float f[16];
    *(float4*)(f)    = *(const float4*)(p);
    *(float4*)(f+4)  = *(const float4*)(p+4);
    *(float4*)(f+8)  = *(const float4*)(p+8);
    *(float4*)(f+12) = *(const float4*)(p+12);
    uint4* dst = (uint4*)lds;
#pragma unroll
    for (int c = 0; c < 2; ++c) {
        ushort tmp[8];
#pragma unroll
        for (int e = 0; e < 8; ++e) tmp[e] = f2bf(f[c*8+e]);
        int chunk = cseg*2 + c;
        dst[row*8 + (chunk ^ (row & 7))] = *(uint4*)tmp;
    }
}

__device__ __forceinline__ bf16x8 frag_ld(const ushort* lds, int row, int chunk)
{
    uint4 v = ((const uint4*)lds)[row*8 + (chunk ^ (row & 7))];
    return __builtin_bit_cast(bf16x8, v);
}

// ---------------------------------------------------------------------------
// MFMA attention: block = (b, h, 64-query tile); 4 waves x 16 query rows.
// Pass 1: online row max/sum over K tiles. Pass 2: recompute S, write
// normalized P to attn_out, accumulate ctx = P*V via MFMA.
// Q,K layout [B,H,S,DK]; V pre-transposed [B,H,DK,SQ].
// ---------------------------------------------------------------------------
__global__ __launch_bounds__(256)
void attn_mfma(const float* __restrict__ Q, const float* __restrict__ K,
               const float* __restrict__ Vt, float* __restrict__ attn_out,
               float* __restrict__ ctx)
{
    __shared__ ushort Ks[4096];
    __shared__ ushort Vs[4096];
    __shared__ ushort Ps[4][1024];

    const int t    = threadIdx.x;
    const int lane = t & 63;
    const int w    = t >> 6;
    const int lr   = lane & 15, kg = lane >> 4;
    const int qt = blockIdx.x, hh = blockIdx.y, b = blockIdx.z;
    const int bh = b*H + hh;
    const size_t base = (size_t)bh * SQ * DK;

    // Q fragments: wave w covers query rows qt*64 + w*16 .. +15
    bf16x8 qf[2];
    {
        const float* qrow = Q + base + (size_t)(qt*64 + w*16 + lr) * DK + kg*8;
#pragma unroll
        for (int k2 = 0; k2 < 2; ++k2) {
            float f[8];
            *(float4*)(f)   = *(const float4*)(qrow + k2*32);
            *(float4*)(f+4) = *(const float4*)(qrow + k2*32 + 4);
            bf16x8 q8;
#pragma unroll
            for (int e = 0; e < 8; ++e) q8[e] = (short)f2bf(f[e]);
            qf[k2] = q8;
        }
    }

    float mrow[4], lrow[4];
#pragma unroll
    for (int r = 0; r < 4; ++r) { mrow[r] = -1e30f; lrow[r] = 0.f; }

    // ---- pass 1: running max & sum ----
    for (int kt = 0; kt < 16; ++kt) {
        __syncthreads();
        stage64(K + base + (size_t)kt*64*DK, DK, Ks, t);
        __syncthreads();
        f32x4 sc[4];
#pragma unroll
        for (int n = 0; n < 4; ++n) {
            f32x4 z = {0.f,0.f,0.f,0.f};
            z = mfma16(qf[0], frag_ld(Ks, n*16+lr, kg),   z);
            z = mfma16(qf[1], frag_ld(Ks, n*16+lr, 4+kg), z);
            sc[n] = z * 0.125f;
        }
#pragma unroll
        for (int r = 0; r < 4; ++r) {
            float v = fmaxf(fmaxf(sc[0][r], sc[1][r]), fmaxf(sc[2][r], sc[3][r]));
#pragma unroll
            for (int msk = 1; msk < 16; msk <<= 1) v = fmaxf(v, __shfl_xor(v, msk, 64));
            float mn = fmaxf(mrow[r], v);
            float e = __expf(sc[0][r]-mn) + __expf(sc[1][r]-mn)
                    + __expf(sc[2][r]-mn) + __expf(sc[3][r]-mn);
#pragma unroll
            for (int msk = 1; msk < 16; msk <<= 1) e += __shfl_xor(e, msk, 64);
            lrow[r] = lrow[r]*__expf(mrow[r]-mn) + e;
            mrow[r] = mn;
        }
    }
    float invl[4];
#pragma unroll
    for (int r = 0; r < 4; ++r) invl[r] = 1.0f / lrow[r];

    // ---- pass 2: P write + PV ----
    f32x4 acc_o[4];
#pragma unroll
    for (int n = 0; n < 4; ++n) acc_o[n] = (f32x4){0.f,0.f,0.f,0.f};

    float* ap0 = attn_out + ((size_t)bh*SQ + (size_t)qt*64 + w*16)*SQ;

    for (int kt = 0; kt < 16; ++kt) {
        __syncthreads();
        stage64(K  + base + (size_t)kt*64*DK, DK, Ks, t);
        stage64(Vt + base + (size_t)kt*64,    SQ, Vs, t);
        __syncthreads();
        f32x4 sc[4];
#pragma unroll
        for (int n = 0; n < 4; ++n) {
            f32x4 z = {0.f,0.f,0.f,0.f};
            z = mfma16(qf[0], frag_ld(Ks, n*16+lr, kg),   z);
            z = mfma16(qf[1], frag_ld(Ks, n*16+lr, 4+kg), z);
            sc[n] = z * 0.125f;
        }
        // normalized probabilities -> global attn + LDS (bf16) for PV
#pragma unroll
        for (int n = 0; n < 4; ++n) {
#pragma unroll
            for (int r = 0; r < 4; ++r) {
                float p = __expf(sc[n][r] - mrow[r]) * invl[r];
                int row = kg*4 + r, col = n*16 + lr;
                ap0[(size_t)row*SQ + kt*64 + col] = p;
                Ps[w][row*64 + ((col>>3) ^ (row&7))*8 + (col&7)] = f2bf(p);
            }
        }
        bf16x8 a0 = frag_ld(Ps[w], lr, kg);
        bf16x8 a1 = frag_ld(Ps[w], lr, 4+kg);
#pragma unroll
        for (int n = 0; n < 4; ++n) {
            acc_o[n] = mfma16(a0, frag_ld(Vs, n*16+lr, kg),   acc_o[n]);
            acc_o[n] = mfma16(a1, frag_ld(Vs, n*16+lr, 4+kg), acc_o[n]);
        }
    }

    // ctx write in [B,S,D] layout
    float* cp = ctx + ((size_t)b*SQ + (size_t)qt*64 + w*16)*D + hh*DK;
#pragma unroll
    for (int n = 0; n < 4; ++n)
#pragma unroll
        for (int r = 0; r < 4; ++r)
            cp[(size_t)(kg*4+r)*D + n*16 + lr] = acc_o[n][r];
}

// ---------------------------------------------------------------------------
// LayerNorm: one block per row
// ---------------------------------------------------------------------------
__global__ __launch_bounds__(256)
void ln_k(const float* __restrict__ hbuf, const float* __restrict__ gamma,
          const float* __restrict__ beta, float* __restrict__ y)
{
    const int row = blockIdx.x;
    const float* hr = hbuf + (size_t)row * D;
    float v[4];
    float s = 0.f, sq = 0.f;
#pragma unroll
    for (int l = 0; l < 4; ++l) {
        v[l] = hr[threadIdx.x + l*256];
        s += v[l];
        sq = fmaf(v[l], v[l], sq);
    }
#pragma unroll
    for (int o = 32; o >= 1; o >>= 1) {
        s  += __shfl_down(s, o, 64);
        sq += __shfl_down(sq, o, 64);
    }
    __shared__ float rs_[4], rq_[4], mu_s, rstd_s;
    int wid = threadIdx.x >> 6;
    if ((threadIdx.x & 63) == 0) { rs_[wid] = s; rq_[wid] = sq; }
    __syncthreads();
    if (threadIdx.x == 0) {
        float S  = rs_[0]+rs_[1]+rs_[2]+rs_[3];
        float Q2 = rq_[0]+rq_[1]+rq_[2]+rq_[3];
        float mu  = S * (1.0f/1024.0f);
        float var = Q2 * (1.0f/1024.0f) - mu*mu;
        mu_s = mu;
        rstd_s = rsqrtf(var + 1e-5f);
    }
    __syncthreads();
    float mu = mu_s, rstd = rstd_s;
#pragma unroll
    for (int l = 0; l < 4; ++l) {
        int c = threadIdx.x + l*256;
        y[(size_t)row*D + c] = (v[l]-mu)*rstd*gamma[c] + beta[c];
    }
}

// ---------------------------------------------------------------------------
extern "C" void kernel_launch(void* const* d_in, const int* in_sizes, int n_in,
                              void* d_out, int out_size, void* d_ws, size_t ws_size,
                              hipStream_t stream)
{
    const float* x     = (const float*)d_in[0];
    const float* Wq    = (const float*)d_in[1];
    const float* bq    = (const float*)d_in[2];
    const float* Wk    = (const float*)d_in[3];
    const float* bk    = (const float*)d_in[4];
    const float* Wv    = (const float*)d_in[5];
    const float* bv    = (const float*)d_in[6];
    const float* Wo    = (const float*)d_in[7];
    const float* bo    = (const float*)d_in[8];
    const float* gamma = (const float*)d_in[9];
    const float* beta  = (const float*)d_in[10];

    float* y    = (float*)d_out;                     // [8,1024,1024]
    float* attn = (float*)d_out + (size_t)NROW * D;  // [8,16,1024,1024]

    const size_t SZ = (size_t)NROW * D;              // 32MB each
    float* ws = (float*)d_ws;
    float* Qb = ws;            // [B,H,S,DK]
    float* Kb = ws + SZ;       // [B,H,S,DK]
    float* Vb = ws + 2*SZ;     // [B,H,DK,SQ]  (transposed)
    float* Cb = ws + 3*SZ;     // ctx [B,S,D]
    float* Hb = Qb;            // h reuses Q region (Q dead after attention)

    dim3 gg(16, 128), bb(256);
    gemm_bt<0><<<gg, bb, 0, stream>>>(x, Wq, bq, nullptr, Qb);
    gemm_bt<0><<<gg, bb, 0, stream>>>(x, Wk, bk, nullptr, Kb);
    gemm_bt<2><<<gg, bb, 0, stream>>>(x, Wv, bv, nullptr, Vb);

    dim3 ga(16, H, NB);
    attn_mfma<<<ga, 256, 0, stream>>>(Qb, Kb, Vb, attn, Cb);

    gemm_bt<1><<<gg, bb, 0, stream>>>(Cb, Wo, bo, x, Hb);

    ln_k<<<NROW, 256, 0, stream>>>(Hb, gamma, beta, y);
}

// Round 3
// 395.686 us; speedup vs baseline: 14.6105x; 3.4442x over previous
//
#include <hip/hip_runtime.h>
#include <math.h>

#define D 1024
#define H 16
#define DK 64
#define SQ 1024
#define NB 8
#define NROW (NB*SQ)   // 8192

typedef __attribute__((ext_vector_type(8))) short bf16x8;
typedef __attribute__((ext_vector_type(4))) float f32x4;

__device__ __forceinline__ ushort f2bf(float x){
    unsigned u = __builtin_bit_cast(unsigned, x);
    u += 0x7FFFu + ((u >> 16) & 1u);
    return (ushort)(u >> 16);
}

__device__ __forceinline__ f32x4 mfma16(bf16x8 a, bf16x8 b, f32x4 c){
    return __builtin_amdgcn_mfma_f32_16x16x32_bf16(a, b, c, 0, 0, 0);
}

__device__ __forceinline__ void gload16(const void* g, void* l){
    __builtin_amdgcn_global_load_lds(
        (const __attribute__((address_space(1))) unsigned int*)g,
        (__attribute__((address_space(3))) unsigned int*)l, 16, 0, 0);
}

// ---------------------------------------------------------------------------
// fp32 -> bf16 conversion kernels
// ---------------------------------------------------------------------------
__global__ __launch_bounds__(256)
void cvtX(const float* __restrict__ s, ushort* __restrict__ d)
{
    int i = blockIdx.x*256 + threadIdx.x;          // handles 8 floats
    float4 a = ((const float4*)s)[i*2];
    float4 b = ((const float4*)s)[i*2+1];
    ushort tmp[8] = {f2bf(a.x),f2bf(a.y),f2bf(a.z),f2bf(a.w),
                     f2bf(b.x),f2bf(b.y),f2bf(b.z),f2bf(b.w)};
    ((uint4*)d)[i] = *(uint4*)tmp;
}

__global__ __launch_bounds__(256)
void cvtW(const float* s0,const float* s1,const float* s2,const float* s3,
          ushort* d0,ushort* d1,ushort* d2,ushort* d3)
{
    const float* s; ushort* d;
    switch (blockIdx.y){
        case 0: s=s0; d=d0; break;
        case 1: s=s1; d=d1; break;
        case 2: s=s2; d=d2; break;
        default: s=s3; d=d3; break;
    }
    int i = blockIdx.x*256 + threadIdx.x;
    float4 a = ((const float4*)s)[i*2];
    float4 b = ((const float4*)s)[i*2+1];
    ushort tmp[8] = {f2bf(a.x),f2bf(a.y),f2bf(a.z),f2bf(a.w),
                     f2bf(b.x),f2bf(b.y),f2bf(b.z),f2bf(b.w)};
    ((uint4*)d)[i] = *(uint4*)tmp;
}

// ---------------------------------------------------------------------------
// bf16 MFMA GEMM (m97 structure): C[i][j] = sum_k A[i][k]*W[j][k] + bias
// 128x128 tile, BK=32, 4 waves x 64x64. global_load_lds w/ pre-swizzled src.
// MODE 0: bf16 out, [B,H,S,DK] scatter    (Q,K)
// MODE 2: bf16 out, [B,H,DK,SQ] scatter   (V transposed)
// MODE 1: fp32 out + residual, plain [i][j]
// ---------------------------------------------------------------------------
__device__ __forceinline__ void stage_g(const ushort* __restrict__ g, int ldg,
                                        ushort* lds, int t)
{
    // 128 rows x 32 cols bf16; 4 x 16B chunks/row; swizzle chunk ^= row&3
#pragma unroll
    for (int i = 0; i < 2; ++i){
        int c = i*256 + t;
        int row = c >> 2, sc = c & 3;
        int gch = sc ^ (row & 3);
        gload16(g + (size_t)row*ldg + gch*8, lds + c*8);
    }
}

__device__ __forceinline__ bf16x8 gfrag(const ushort* lds, int row, int kc)
{
    uint4 v = ((const uint4*)lds)[row*4 + (kc ^ (row & 3))];
    return __builtin_bit_cast(bf16x8, v);
}

template<int MODE>
__global__ __launch_bounds__(256)
void gemm_mfma(const ushort* __restrict__ A, const ushort* __restrict__ W,
               const float* __restrict__ bias, const float* __restrict__ resid,
               void* __restrict__ out)
{
    __shared__ ushort As[4096];   // 8KB
    __shared__ ushort Bs[4096];
    const int t = threadIdx.x, lane = t & 63, w = t >> 6;
    const int wr = w >> 1, wc = w & 1, lr = lane & 15, kg = lane >> 4;
    const int i0 = blockIdx.y * 128, j0 = blockIdx.x * 128;
    const ushort* Ab = A + (size_t)i0 * 1024;
    const ushort* Wb = W + (size_t)j0 * 1024;

    f32x4 acc[4][4];
#pragma unroll
    for (int m = 0; m < 4; ++m)
#pragma unroll
        for (int n = 0; n < 4; ++n) acc[m][n] = (f32x4){0.f,0.f,0.f,0.f};

    for (int k0 = 0; k0 < 1024; k0 += 32){
        __syncthreads();
        stage_g(Ab + k0, 1024, As, t);
        stage_g(Wb + k0, 1024, Bs, t);
        __syncthreads();
        bf16x8 af[4], bfr[4];
#pragma unroll
        for (int m = 0; m < 4; ++m) af[m]  = gfrag(As, wr*64 + m*16 + lr, kg);
#pragma unroll
        for (int n = 0; n < 4; ++n) bfr[n] = gfrag(Bs, wc*64 + n*16 + lr, kg);
#pragma unroll
        for (int m = 0; m < 4; ++m)
#pragma unroll
            for (int n = 0; n < 4; ++n)
                acc[m][n] = mfma16(af[m], bfr[n], acc[m][n]);
    }

#pragma unroll
    for (int m = 0; m < 4; ++m){
        int rt = i0 + wr*64 + m*16 + kg*4;
#pragma unroll
        for (int n = 0; n < 4; ++n){
            int ct = j0 + wc*64 + n*16 + lr;
            float bj = bias[ct];
#pragma unroll
            for (int j = 0; j < 4; ++j){
                int i = rt + j;
                float v = acc[m][n][j] + bj;
                if (MODE == 0){
                    int b = i >> 10, s = i & 1023, hh = ct >> 6, d = ct & 63;
                    ((ushort*)out)[(((size_t)b*H + hh)*SQ + s)*DK + d] = f2bf(v);
                } else if (MODE == 2){
                    int b = i >> 10, s = i & 1023, hh = ct >> 6, d = ct & 63;
                    ((ushort*)out)[(((size_t)b*H + hh)*DK + d)*SQ + s] = f2bf(v);
                } else {
                    ((float*)out)[(size_t)i*1024 + ct] = v + resid[(size_t)i*1024 + ct];
                }
            }
        }
    }
}

// ---------------------------------------------------------------------------
// MFMA attention, bf16 inputs. Block = (b,h,64-query tile); 4 waves x 16 rows.
// Q,K: [B,H,S,DK] bf16. Vt: [B,H,DK,SQ] bf16. ctx out: [B,S,D] bf16.
// ---------------------------------------------------------------------------
__device__ __forceinline__ void stage_attn(const ushort* __restrict__ g, int ldg,
                                           ushort* lds, int t)
{
    // 64 rows x 64 cols bf16; 8 x 16B chunks/row; swizzle chunk ^= row&7
#pragma unroll
    for (int i = 0; i < 2; ++i){
        int c = i*256 + t;
        int row = c >> 3, sc = c & 7;
        int gch = sc ^ (row & 7);
        gload16(g + (size_t)row*ldg + gch*8, lds + c*8);
    }
}

__device__ __forceinline__ bf16x8 frag_ld(const ushort* lds, int row, int chunk)
{
    uint4 v = ((const uint4*)lds)[row*8 + (chunk ^ (row & 7))];
    return __builtin_bit_cast(bf16x8, v);
}

__global__ __launch_bounds__(256)
void attn_mfma(const ushort* __restrict__ Q, const ushort* __restrict__ K,
               const ushort* __restrict__ Vt, float* __restrict__ attn_out,
               ushort* __restrict__ ctx)
{
    __shared__ ushort Ks[4096];
    __shared__ ushort Vs[4096];
    __shared__ ushort Ps[4][1024];

    const int t    = threadIdx.x;
    const int lane = t & 63;
    const int w    = t >> 6;
    const int lr   = lane & 15, kg = lane >> 4;
    const int qt = blockIdx.x, hh = blockIdx.y, b = blockIdx.z;
    const int bh = b*H + hh;
    const size_t base = (size_t)bh * SQ * DK;

    bf16x8 qf[2];
    {
        const ushort* qrow = Q + base + (size_t)(qt*64 + w*16 + lr) * DK + kg*8;
        qf[0] = __builtin_bit_cast(bf16x8, *(const uint4*)qrow);
        qf[1] = __builtin_bit_cast(bf16x8, *(const uint4*)(qrow + 32));
    }

    float mrow[4], lrow[4];
#pragma unroll
    for (int r = 0; r < 4; ++r) { mrow[r] = -1e30f; lrow[r] = 0.f; }

    // ---- pass 1: running max & sum ----
    for (int kt = 0; kt < 16; ++kt) {
        __syncthreads();
        stage_attn(K + base + (size_t)kt*64*DK, DK, Ks, t);
        __syncthreads();
        f32x4 sc[4];
#pragma unroll
        for (int n = 0; n < 4; ++n) {
            f32x4 z = {0.f,0.f,0.f,0.f};
            z = mfma16(qf[0], frag_ld(Ks, n*16+lr, kg),   z);
            z = mfma16(qf[1], frag_ld(Ks, n*16+lr, 4+kg), z);
            sc[n] = z * 0.125f;
        }
#pragma unroll
        for (int r = 0; r < 4; ++r) {
            float v = fmaxf(fmaxf(sc[0][r], sc[1][r]), fmaxf(sc[2][r], sc[3][r]));
#pragma unroll
            for (int msk = 1; msk < 16; msk <<= 1) v = fmaxf(v, __shfl_xor(v, msk, 64));
            float mn = fmaxf(mrow[r], v);
            float e = __expf(sc[0][r]-mn) + __expf(sc[1][r]-mn)
                    + __expf(sc[2][r]-mn) + __expf(sc[3][r]-mn);
#pragma unroll
            for (int msk = 1; msk < 16; msk <<= 1) e += __shfl_xor(e, msk, 64);
            lrow[r] = lrow[r]*__expf(mrow[r]-mn) + e;
            mrow[r] = mn;
        }
    }
    float invl[4];
#pragma unroll
    for (int r = 0; r < 4; ++r) invl[r] = 1.0f / lrow[r];

    // ---- pass 2: P write + PV ----
    f32x4 acc_o[4];
#pragma unroll
    for (int n = 0; n < 4; ++n) acc_o[n] = (f32x4){0.f,0.f,0.f,0.f};

    float* ap0 = attn_out + ((size_t)bh*SQ + (size_t)qt*64 + w*16)*SQ;

    for (int kt = 0; kt < 16; ++kt) {
        __syncthreads();
        stage_attn(K  + base + (size_t)kt*64*DK, DK, Ks, t);
        stage_attn(Vt + base + (size_t)kt*64,    SQ, Vs, t);
        __syncthreads();
        f32x4 sc[4];
#pragma unroll
        for (int n = 0; n < 4; ++n) {
            f32x4 z = {0.f,0.f,0.f,0.f};
            z = mfma16(qf[0], frag_ld(Ks, n*16+lr, kg),   z);
            z = mfma16(qf[1], frag_ld(Ks, n*16+lr, 4+kg), z);
            sc[n] = z * 0.125f;
        }
#pragma unroll
        for (int n = 0; n < 4; ++n) {
#pragma unroll
            for (int r = 0; r < 4; ++r) {
                float p = __expf(sc[n][r] - mrow[r]) * invl[r];
                int row = kg*4 + r, col = n*16 + lr;
                ap0[(size_t)row*SQ + kt*64 + col] = p;
                Ps[w][row*64 + ((col>>3) ^ (row&7))*8 + (col&7)] = f2bf(p);
            }
        }
        bf16x8 a0 = frag_ld(Ps[w], lr, kg);
        bf16x8 a1 = frag_ld(Ps[w], lr, 4+kg);
#pragma unroll
        for (int n = 0; n < 4; ++n) {
            acc_o[n] = mfma16(a0, frag_ld(Vs, n*16+lr, kg),   acc_o[n]);
            acc_o[n] = mfma16(a1, frag_ld(Vs, n*16+lr, 4+kg), acc_o[n]);
        }
    }

    ushort* cp = ctx + ((size_t)b*SQ + (size_t)qt*64 + w*16)*D + hh*DK;
#pragma unroll
    for (int n = 0; n < 4; ++n)
#pragma unroll
        for (int r = 0; r < 4; ++r)
            cp[(size_t)(kg*4+r)*D + n*16 + lr] = f2bf(acc_o[n][r]);
}

// ---------------------------------------------------------------------------
// LayerNorm: one block per row
// ---------------------------------------------------------------------------
__global__ __launch_bounds__(256)
void ln_k(const float* __restrict__ hbuf, const float* __restrict__ gamma,
          const float* __restrict__ beta, float* __restrict__ y)
{
    const int row = blockIdx.x;
    const float* hr = hbuf + (size_t)row * D;
    float v[4];
    float s = 0.f, sq = 0.f;
#pragma unroll
    for (int l = 0; l < 4; ++l) {
        v[l] = hr[threadIdx.x + l*256];
        s += v[l];
        sq = fmaf(v[l], v[l], sq);
    }
#pragma unroll
    for (int o = 32; o >= 1; o >>= 1) {
        s  += __shfl_down(s, o, 64);
        sq += __shfl_down(sq, o, 64);
    }
    __shared__ float rs_[4], rq_[4], mu_s, rstd_s;
    int wid = threadIdx.x >> 6;
    if ((threadIdx.x & 63) == 0) { rs_[wid] = s; rq_[wid] = sq; }
    __syncthreads();
    if (threadIdx.x == 0) {
        float S  = rs_[0]+rs_[1]+rs_[2]+rs_[3];
        float Q2 = rq_[0]+rq_[1]+rq_[2]+rq_[3];
        float mu  = S * (1.0f/1024.0f);
        float var = Q2 * (1.0f/1024.0f) - mu*mu;
        mu_s = mu;
        rstd_s = rsqrtf(var + 1e-5f);
    }
    __syncthreads();
    float mu = mu_s, rstd = rstd_s;
#pragma unroll
    for (int l = 0; l < 4; ++l) {
        int c = threadIdx.x + l*256;
        y[(size_t)row*D + c] = (v[l]-mu)*rstd*gamma[c] + beta[c];
    }
}

// ---------------------------------------------------------------------------
extern "C" void kernel_launch(void* const* d_in, const int* in_sizes, int n_in,
                              void* d_out, int out_size, void* d_ws, size_t ws_size,
                              hipStream_t stream)
{
    const float* x     = (const float*)d_in[0];
    const float* Wq    = (const float*)d_in[1];
    const float* bq    = (const float*)d_in[2];
    const float* Wk    = (const float*)d_in[3];
    const float* bk    = (const float*)d_in[4];
    const float* Wv    = (const float*)d_in[5];
    const float* bv    = (const float*)d_in[6];
    const float* Wo    = (const float*)d_in[7];
    const float* bo    = (const float*)d_in[8];
    const float* gamma = (const float*)d_in[9];
    const float* beta  = (const float*)d_in[10];

    float* y    = (float*)d_out;                     // [8,1024,1024]
    float* attn = (float*)d_out + (size_t)NROW * D;  // [8,16,1024,1024]

    const size_t SZ = (size_t)NROW * D;              // 8M elements
    const size_t WSZ = (size_t)D * D;                // 1M elements
    ushort* ws  = (ushort*)d_ws;
    ushort* xb  = ws;                 // [8192][1024] bf16
    ushort* Wqb = xb  + SZ;
    ushort* Wkb = Wqb + WSZ;
    ushort* Wvb = Wkb + WSZ;
    ushort* Wob = Wvb + WSZ;
    ushort* Qb  = Wob + WSZ;          // [B,H,S,DK] bf16
    ushort* Kb  = Qb  + SZ;           // [B,H,S,DK] bf16
    ushort* Vtb = Kb  + SZ;           // [B,H,DK,SQ] bf16
    ushort* Cb  = Vtb + SZ;           // ctx [B,S,D] bf16
    float*  Hb  = (float*)(Cb + SZ);  // [8192][1024] fp32

    cvtX<<<4096, 256, 0, stream>>>(x, xb);
    cvtW<<<dim3(512, 4), 256, 0, stream>>>(Wq, Wk, Wv, Wo, Wqb, Wkb, Wvb, Wob);

    dim3 gg(8, 64), bb(256);
    gemm_mfma<0><<<gg, bb, 0, stream>>>(xb, Wqb, bq, nullptr, Qb);
    gemm_mfma<0><<<gg, bb, 0, stream>>>(xb, Wkb, bk, nullptr, Kb);
    gemm_mfma<2><<<gg, bb, 0, stream>>>(xb, Wvb, bv, nullptr, Vtb);

    dim3 ga(16, H, NB);
    attn_mfma<<<ga, 256, 0, stream>>>(Qb, Kb, Vtb, attn, Cb);

    gemm_mfma<1><<<gg, bb, 0, stream>>>(Cb, Wob, bo, x, Hb);

    ln_k<<<NROW, 256, 0, stream>>>(Hb, gamma, beta, y);
}